// Round 18
// baseline (110.905 us; speedup 1.0000x reference)
//
#include <hip/hip_runtime.h>

// Problem constants (setup_inputs is fixed):
//   b=4, n1=16384, n2=4096  -> N1=65536 fine points, N2=16384 coarse points
//   Cin(x1)=64, Cin(x2)=128, Cout=64
#define N1T 65536
#define N2T 16384
#define COUT 64
#define CH 192            // Cout*3 channels, point-major
#define GRD 8             // knn grid resolution per dim
#define HCELL 0.125f

typedef unsigned short bhalf;
typedef __attribute__((ext_vector_type(8))) short short8;   // 8 bf16 (4 VGPRs)
typedef __attribute__((ext_vector_type(4))) float f32x4;    // MFMA C/D

__device__ __forceinline__ bhalf f2bf(float f) {
    unsigned u = __float_as_uint(f);
    return (bhalf)((u + 0x7FFFu + ((u >> 16) & 1u)) >> 16);   // RNE
}
__device__ __forceinline__ float bf2f(bhalf h) {
    return __uint_as_float(((unsigned)h) << 16);
}

// ---------------------------------------------------------------------------
// Weight preconversion fp32 -> split bf16 (hi + lo residual), once, tiny.
// ---------------------------------------------------------------------------
__global__ __launch_bounds__(256) void wconv_kernel(
    const float* __restrict__ w1f, const float* __restrict__ w1d,
    const float* __restrict__ w2f, const float* __restrict__ w2d,
    bhalf* __restrict__ o1fh, bhalf* __restrict__ o1fl,
    bhalf* __restrict__ o1dh, bhalf* __restrict__ o1dl,
    bhalf* __restrict__ o2fh, bhalf* __restrict__ o2fl,
    bhalf* __restrict__ o2dh, bhalf* __restrict__ o2dl) {
    const int i = blockIdx.x * 256 + threadIdx.x;   // grid 32 -> 8192
    if (i < 4096) {
        const float a = w1f[i]; const bhalf ah = f2bf(a);
        o1fh[i] = ah; o1fl[i] = f2bf(a - bf2f(ah));
        const float b = w1d[i]; const bhalf bh = f2bf(b);
        o1dh[i] = bh; o1dl[i] = f2bf(b - bf2f(bh));
    }
    const float a = w2f[i]; const bhalf ah = f2bf(a);
    o2fh[i] = ah; o2fl[i] = f2bf(a - bf2f(ah));
    const float b = w2d[i]; const bhalf bh = f2bf(b);
    o2dh[i] = bh; o2dl[i] = f2bf(b - bf2f(bh));
}

// ---------------------------------------------------------------------------
// VN linear + leaky-ReLU via SPLIT-PRECISION bf16 MFMA.
// W.x ~= Wh.xh + Wl.xh + Wh.xl (~2^-16 relative; plain bf16 failed at
// absmax 0.32: VN amplifies d-rounding by |p|/|d|).
// 32-pt tiles, 512 thr = 8 light waves; wave w owns (ot=w&3, sW=w>>2).
// R18 schedule (T14 issue-early/consume-late for EVERY large load group):
//   load(t0)->LDS; issue stage(t1); issue gather(t0); barrier;
//   MFMA+VN(t0); write(t1)->LDS; store(t0); issue gather(t1); barrier;
//   MFMA+VN(t1); store(t1)
// R17 left each tile's 9-float4 gather exposed inside its compute phase
// (MLP~3, HBM 2.2TB/s); now 12 wave-loads drain under each MFMA phase.
// LDS XOR swizzle col^=((pt>>2)&3)<<3. CM=true fuses interpolation-add.
// D-layout (m89): col=lane&15 -> point, row=(lane>>4)*4+reg -> o.
// ---------------------------------------------------------------------------
template<int CIN, int N, bool CM, int NT>
__global__ __launch_bounds__(512) void vn_mfma_kernel(
    const float* __restrict__ x,    // [CIN][3][N]
    const bhalf* __restrict__ wfh, const bhalf* __restrict__ wfl,  // [COUT][CIN]
    const bhalf* __restrict__ wdh, const bhalf* __restrict__ wdl,
    const int*   __restrict__ idxs, // [3][N1] (CM only)
    const float* __restrict__ wts,  // [3][N1] (CM only)
    const float* __restrict__ y2t,  // [N2][192] (CM only)
    float* __restrict__ out)
{
    constexpr int ROWS = CIN * 3;
    constexpr int LDSC = CIN * 3 + 8;    // ushort row stride (16B-aligned)
    constexpr int NB   = (NT > 1) ? 2 : 1;
    constexpr int NLD  = ROWS * 8 / 512; // float4 rounds/tile: 3 (vn1) / 6 (vn2)
    __shared__ __align__(16) bhalf xs_h[NB][32][LDSC];
    __shared__ __align__(16) bhalf xs_l[NB][32][LDSC];

    const int tid  = threadIdx.x;
    const int lane = tid & 63;
    const int wave = tid >> 6;                  // 0..7
    const int r16  = lane & 15;
    const int hh   = lane >> 4;                 // k-group 0..3
    const int ot   = wave & 3;                  // o-tile (16 o's)
    const int sW   = wave >> 2;                 // point subtile (16 pts)
    const int pt   = sW * 16 + r16;
    const int tile0 = blockIdx.x * NT;
    const int chb  = ot * 48 + hh * 12;

    // ---- per-tile neighbor metadata, prefetched for ALL tiles (CM) ----
    int gk[NT][3]; float gw[NT][3];
    if constexpr (CM) {
#pragma unroll
        for (int t = 0; t < NT; ++t) {
            const int n = (tile0 + t) * 32 + pt;
#pragma unroll
            for (int r = 0; r < 3; ++r) {
                gk[t][r] = idxs[r * N1T + n];
                gw[t][r] = wts[r * N1T + n];
            }
        }
    }

    const int wofs = (ot * 16 + r16) * CIN + hh * 8;
    const bhalf* __restrict__ pfh = wfh + wofs;
    const bhalf* __restrict__ pfl = wfl + wofs;
    const bhalf* __restrict__ pdh = wdh + wofs;
    const bhalf* __restrict__ pdl = wdl + wofs;
    // read-side swizzle: (pt>>2)&3 == (r16>>2)&3 (sW*16>>2 ≡ 0 mod 4)
    const int hs = ((hh ^ (r16 >> 2)) & 3) * 8;

    auto LOADT = [&](float4 (&st)[NLD], int t) {
#pragma unroll
        for (int r = 0; r < NLD; ++r) {
            const int i4 = r * 512 + tid;
            const int row = i4 >> 3, p4 = i4 & 7;   // row = c*3+v
            st[r] = *(const float4*)&x[(size_t)row * N + (size_t)(tile0 + t) * 32 + p4 * 4];
        }
    };
    auto WRITET = [&](const float4 (&st)[NLD], int b) {
#pragma unroll
        for (int r = 0; r < NLD; ++r) {
            const int i4 = r * 512 + tid;
            const int row = i4 >> 3, p4 = i4 & 7;
            const int c = row / 3, vv = row - c * 3;
            const int colS = (vv * CIN + c) ^ ((p4 & 3) << 3);
            const float vals[4] = {st[r].x, st[r].y, st[r].z, st[r].w};
#pragma unroll
            for (int j = 0; j < 4; ++j) {
                const bhalf h = f2bf(vals[j]);
                xs_h[b][p4*4+j][colS] = h;
                xs_l[b][p4*4+j][colS] = f2bf(vals[j] - bf2f(h));
            }
        }
    };
    // issue the 9 gather loads for tile t (independent, drain under MFMA)
    auto GATHER_ISSUE = [&](float4 (&g0)[3], float4 (&g1)[3], float4 (&g2)[3], int t) {
        const float* __restrict__ r0 = y2t + (size_t)gk[t][0] * CH + chb;
        const float* __restrict__ r1 = y2t + (size_t)gk[t][1] * CH + chb;
        const float* __restrict__ r2 = y2t + (size_t)gk[t][2] * CH + chb;
#pragma unroll
        for (int q = 0; q < 3; ++q) {
            g0[q] = *(const float4*)&r0[q * 4];
            g1[q] = *(const float4*)&r1[q * 4];
            g2[q] = *(const float4*)&r2[q * 4];
        }
    };
    auto MFMA_VN = [&](float (&rr)[12], int b) {
        const f32x4 zero = {0.f, 0.f, 0.f, 0.f};
        f32x4 accP[3], accD[3];
#pragma unroll
        for (int v = 0; v < 3; ++v) { accP[v] = zero; accD[v] = zero; }
#pragma unroll
        for (int k = 0; k < CIN / 32; ++k) {
            const short8 afh = *(const short8*)(pfh + k * 32);
            const short8 afl = *(const short8*)(pfl + k * 32);
            const short8 adh = *(const short8*)(pdh + k * 32);
            const short8 adl = *(const short8*)(pdl + k * 32);
#pragma unroll
            for (int v = 0; v < 3; ++v) {
                const short8 bh = *(const short8*)&xs_h[b][pt][v * CIN + k * 32 + hs];
                const short8 bl = *(const short8*)&xs_l[b][pt][v * CIN + k * 32 + hs];
                accP[v] = __builtin_amdgcn_mfma_f32_16x16x32_bf16(afh, bh, accP[v], 0, 0, 0);
                accP[v] = __builtin_amdgcn_mfma_f32_16x16x32_bf16(afl, bh, accP[v], 0, 0, 0);
                accP[v] = __builtin_amdgcn_mfma_f32_16x16x32_bf16(afh, bl, accP[v], 0, 0, 0);
                accD[v] = __builtin_amdgcn_mfma_f32_16x16x32_bf16(adh, bh, accD[v], 0, 0, 0);
                accD[v] = __builtin_amdgcn_mfma_f32_16x16x32_bf16(adl, bh, accD[v], 0, 0, 0);
                accD[v] = __builtin_amdgcn_mfma_f32_16x16x32_bf16(adh, bl, accD[v], 0, 0, 0);
            }
        }
#pragma unroll
        for (int reg = 0; reg < 4; ++reg) {
            const float p0 = accP[0][reg], p1 = accP[1][reg], p2 = accP[2][reg];
            const float q0 = accD[0][reg], q1 = accD[1][reg], q2 = accD[2][reg];
            const float dot = p0*q0 + p1*q1 + p2*q2;
            const float dd  = q0*q0 + q1*q1 + q2*q2;
            const float coef = (dot < 0.f) ? (0.8f * dot / (dd + 1e-6f)) : 0.f;
            rr[reg*3+0] = p0 - coef * q0;
            rr[reg*3+1] = p1 - coef * q1;
            rr[reg*3+2] = p2 - coef * q2;
        }
    };
    auto STORE_CM = [&](const float (&rr)[12],
                        const float4 (&g0)[3], const float4 (&g1)[3],
                        const float4 (&g2)[3], int t) {
        const int n = (tile0 + t) * 32 + pt;
        const float w0 = gw[t][0], w1 = gw[t][1], w2 = gw[t][2];
#pragma unroll
        for (int q = 0; q < 3; ++q) {
            const float u0 = w0*g0[q].x + w1*g1[q].x + w2*g2[q].x;
            const float u1 = w0*g0[q].y + w1*g1[q].y + w2*g2[q].y;
            const float u2 = w0*g0[q].z + w1*g1[q].z + w2*g2[q].z;
            const float u3 = w0*g0[q].w + w1*g1[q].w + w2*g2[q].w;
            out[(size_t)(chb + q*4 + 0) * N + n] = rr[q*4+0] + u0;
            out[(size_t)(chb + q*4 + 1) * N + n] = rr[q*4+1] + u1;
            out[(size_t)(chb + q*4 + 2) * N + n] = rr[q*4+2] + u2;
            out[(size_t)(chb + q*4 + 3) * N + n] = rr[q*4+3] + u3;
        }
    };
    auto STORE_PM = [&](const float (&rr)[12], int t) {
        const int n = (tile0 + t) * 32 + pt;
        float* op = out + (size_t)n * CH + chb;
        *(float4*)&op[0] = make_float4(rr[0], rr[1], rr[2],  rr[3]);
        *(float4*)&op[4] = make_float4(rr[4], rr[5], rr[6],  rr[7]);
        *(float4*)&op[8] = make_float4(rr[8], rr[9], rr[10], rr[11]);
    };

    float4 stA[NLD], stB[NLD];
    float4 gA0[3], gA1[3], gA2[3];
    float rr0[12], rr1[12];

    LOADT(stA, 0);
    WRITET(stA, 0);
    if constexpr (NT == 2) {
        LOADT(stB, 1);                       // stage t1: in flight
        if constexpr (CM) GATHER_ISSUE(gA0, gA1, gA2, 0);  // gather t0: in flight
        __syncthreads();                     // buf0 ready
        MFMA_VN(rr0, 0);                     // loads drain under this
        WRITET(stB, 1);
        if constexpr (CM) {
            STORE_CM(rr0, gA0, gA1, gA2, 0); // consume gather t0
            GATHER_ISSUE(gA0, gA1, gA2, 1);  // gather t1: in flight (reuses regs)
        } else {
            STORE_PM(rr0, 0);
        }
        __syncthreads();                     // buf1 ready
        MFMA_VN(rr1, 1);                     // gather t1 drains under this
        if constexpr (CM) STORE_CM(rr1, gA0, gA1, gA2, 1);
        else              STORE_PM(rr1, 1);
    } else {
        if constexpr (CM) GATHER_ISSUE(gA0, gA1, gA2, 0);
        __syncthreads();
        MFMA_VN(rr0, 0);
        if constexpr (CM) STORE_CM(rr0, gA0, gA1, gA2, 0);
        else              STORE_PM(rr0, 0);
    }
}

// ---------------------------------------------------------------------------
// kNN via uniform-grid binning. Branchless full-precision top-3 insert.
// ---------------------------------------------------------------------------
#define KNN_INSERT(d2, j)                                        \
    {                                                            \
        const bool c0 = (d2) < b0;                               \
        const bool c1 = (d2) < b1;                               \
        const bool c2 = (d2) < b2v;                              \
        const float nb2 = c2 ? (c1 ? b1 : (d2)) : b2v;           \
        const int   ni2 = c2 ? (c1 ? i1 : (j))  : i2;            \
        const float nb1 = c1 ? (c0 ? b0 : (d2)) : b1;            \
        const int   ni1 = c1 ? (c0 ? i0 : (j))  : i1;            \
        b0 = c0 ? (d2) : b0;  i0 = c0 ? (j) : i0;                \
        b1 = nb1; i1 = ni1; b2v = nb2; i2 = ni2;                 \
    }

__global__ __launch_bounds__(256) void zero_kernel(int* __restrict__ p, int n) {
    const int i = blockIdx.x * 256 + threadIdx.x;
    if (i < n) p[i] = 0;
}

__device__ __forceinline__ int cell_of(float x, float y, float z) {
    int cx = (int)(x * (float)GRD); cx = cx < 0 ? 0 : (cx > GRD-1 ? GRD-1 : cx);
    int cy = (int)(y * (float)GRD); cy = cy < 0 ? 0 : (cy > GRD-1 ? GRD-1 : cy);
    int cz = (int)(z * (float)GRD); cz = cz < 0 ? 0 : (cz > GRD-1 ? GRD-1 : cz);
    return (cz << 6) | (cy << 3) | cx;
}

__global__ __launch_bounds__(256) void bin_count_kernel(
    const float* __restrict__ p2, int* __restrict__ counts) {
    const int i = blockIdx.x * 256 + threadIdx.x;      // 0..16383
    const float x = p2[i*3+0], y = p2[i*3+1], z = p2[i*3+2];
    const int cell = ((i >> 12) << 9) | cell_of(x, y, z);
    atomicAdd(&counts[cell], 1);
}

// exclusive scan of counts[2048] -> off[0..2048]
__global__ __launch_bounds__(256) void scan_kernel(
    const int* __restrict__ counts, int* __restrict__ off) {
    __shared__ int buf[2][256];
    const int t = threadIdx.x;
    int v[8]; int s = 0;
#pragma unroll
    for (int j = 0; j < 8; ++j) { const int tmp = counts[t*8+j]; v[j] = s; s += tmp; }
    buf[0][t] = s; __syncthreads();
    int src = 0;
    for (int d = 1; d < 256; d <<= 1) {
        int val = buf[src][t];
        if (t >= d) val += buf[src][t - d];
        buf[src ^ 1][t] = val; src ^= 1; __syncthreads();
    }
    const int incl = buf[src][t];
    const int base = incl - s;
#pragma unroll
    for (int j = 0; j < 8; ++j) off[t*8+j] = base + v[j];
    if (t == 255) off[2048] = incl;
}

__global__ __launch_bounds__(256) void bin_scatter_kernel(
    const float* __restrict__ p2, const int* __restrict__ off,
    int* __restrict__ cnt2, float4* __restrict__ binned) {
    const int i = blockIdx.x * 256 + threadIdx.x;      // 0..16383
    const float x = p2[i*3+0], y = p2[i*3+1], z = p2[i*3+2];
    const int cell = ((i >> 12) << 9) | cell_of(x, y, z);
    const int pos = off[cell] + atomicAdd(&cnt2[cell], 1);
    binned[pos] = make_float4(x, y, z, __int_as_float(i));
}

// 4 lanes per query; each scans a quarter of every neighbor cell's range,
// then butterfly shfl-xor merge (width 4). Exact: accept only if 3rd-best
// dist is closer than any unscanned region; else masked rescan (rare).
__global__ __launch_bounds__(256) void knn_grid_kernel(
    const float* __restrict__ p1,      // [N1][3]
    const float4* __restrict__ binned, // [N2] (x,y,z,idx)
    const int* __restrict__ off,       // [2049]
    int*   __restrict__ idx_out,       // [3][N1]
    float* __restrict__ w_out)         // [3][N1]
{
    const int t   = blockIdx.x * 256 + threadIdx.x;
    const int fp  = t >> 2;
    const int sub = t & 3;
    const int bi  = fp >> 14;
    const int cbase = bi << 9;

    const float qx = p1[fp*3+0], qy = p1[fp*3+1], qz = p1[fp*3+2];
    int cx = (int)(qx * (float)GRD); cx = cx < 0 ? 0 : (cx > 7 ? 7 : cx);
    int cy = (int)(qy * (float)GRD); cy = cy < 0 ? 0 : (cy > 7 ? 7 : cy);
    int cz = (int)(qz * (float)GRD); cz = cz < 0 ? 0 : (cz > 7 ? 7 : cz);

    float b0 = 1e30f, b1 = 1e30f, b2v = 1e30f;
    int   i0 = 0,     i1 = 0,     i2 = 0;

    for (int dz = -1; dz <= 1; ++dz)
    for (int dy = -1; dy <= 1; ++dy)
    for (int dx = -1; dx <= 1; ++dx) {
        const int nx = cx + dx, ny = cy + dy, nz = cz + dz;
        if ((unsigned)nx > 7u || (unsigned)ny > 7u || (unsigned)nz > 7u) continue;
        const int c = cbase + (nz << 6) + (ny << 3) + nx;
        const int s = off[c], e = off[c + 1];
        for (int k = s + sub; k < e; k += 4) {
            const float4 c4 = binned[k];
            const float ddx = qx - c4.x, ddy = qy - c4.y, ddz = qz - c4.z;
            const float d2 = fmaf(ddx, ddx, fmaf(ddy, ddy, ddz * ddz));
            const int j = __float_as_int(c4.w);
            KNN_INSERT(d2, j)
        }
    }

    // butterfly merge across the 4 sub-lanes
#pragma unroll
    for (int m = 1; m <= 2; m <<= 1) {
        const float c0v = __shfl_xor(b0, m, 4);
        const float c1v = __shfl_xor(b1, m, 4);
        const float c2v = __shfl_xor(b2v, m, 4);
        const int   j0v = __shfl_xor(i0, m, 4);
        const int   j1v = __shfl_xor(i1, m, 4);
        const int   j2v = __shfl_xor(i2, m, 4);
        KNN_INSERT(c0v, j0v)
        KNN_INSERT(c1v, j1v)
        KNN_INSERT(c2v, j2v)
    }

    // exactness check: nearest unscanned region (walls beyond [0,1] excluded)
    float dw = 1e30f;
    if (cx >= 2) dw = fminf(dw, qx - (float)(cx - 1) * HCELL);
    if (cx <= 5) dw = fminf(dw, (float)(cx + 2) * HCELL - qx);
    if (cy >= 2) dw = fminf(dw, qy - (float)(cy - 1) * HCELL);
    if (cy <= 5) dw = fminf(dw, (float)(cy + 2) * HCELL - qy);
    if (cz >= 2) dw = fminf(dw, qz - (float)(cz - 1) * HCELL);
    if (cz <= 5) dw = fminf(dw, (float)(cz + 2) * HCELL - qz);
    const bool done = b2v < dw * dw;

    if (!done) {   // rare; quad-uniform predicate (post-merge state identical)
        b0 = b1 = b2v = 1e30f; i0 = i1 = i2 = 0;
        const int s = bi << 12, e = (bi + 1) << 12;
        for (int k = s + sub; k < e; k += 4) {
            const float4 c4 = binned[k];
            const float ddx = qx - c4.x, ddy = qy - c4.y, ddz = qz - c4.z;
            const float d2 = fmaf(ddx, ddx, fmaf(ddy, ddy, ddz * ddz));
            const int j = __float_as_int(c4.w);
            KNN_INSERT(d2, j)
        }
#pragma unroll
        for (int m = 1; m <= 2; m <<= 1) {
            const float c0v = __shfl_xor(b0, m, 4);
            const float c1v = __shfl_xor(b1, m, 4);
            const float c2v = __shfl_xor(b2v, m, 4);
            const int   j0v = __shfl_xor(i0, m, 4);
            const int   j1v = __shfl_xor(i1, m, 4);
            const int   j2v = __shfl_xor(i2, m, 4);
            KNN_INSERT(c0v, j0v)
            KNN_INSERT(c1v, j1v)
            KNN_INSERT(c2v, j2v)
        }
    }

    if (sub == 0) {
        const float w0 = 1.f / (b0 + 1e-8f);
        const float w1 = 1.f / (b1 + 1e-8f);
        const float w2 = 1.f / (b2v + 1e-8f);
        const float inv = 1.f / (w0 + w1 + w2);
        idx_out[0*N1T + fp] = i0;
        idx_out[1*N1T + fp] = i1;
        idx_out[2*N1T + fp] = i2;
        w_out[0*N1T + fp] = w0 * inv;
        w_out[1*N1T + fp] = w1 * inv;
        w_out[2*N1T + fp] = w2 * inv;
    }
}

// ---------------------------------------------------------------------------
extern "C" void kernel_launch(void* const* d_in, const int* in_sizes, int n_in,
                              void* d_out, int out_size, void* d_ws, size_t ws_size,
                              hipStream_t stream) {
    const float* p1      = (const float*)d_in[0];
    const float* x1      = (const float*)d_in[1];
    const float* p2      = (const float*)d_in[3];
    const float* x2      = (const float*)d_in[4];
    const float* w1_feat = (const float*)d_in[6];
    const float* w1_dir  = (const float*)d_in[7];
    const float* w2_feat = (const float*)d_in[8];
    const float* w2_dir  = (const float*)d_in[9];
    float* out = (float*)d_out;

    // workspace layout (all chunks 16B-aligned)
    char* ws = (char*)d_ws;
    float*  y2t    = (float*)ws;                 ws += (size_t)N2T * CH * 4;   // 12.58 MB
    int*    idxs   = (int*)ws;                   ws += (size_t)3 * N1T * 4;    // 0.75 MB
    float*  wts    = (float*)ws;                 ws += (size_t)3 * N1T * 4;    // 0.75 MB
    int*    counts = (int*)ws;                   ws += 2048 * 4;
    int*    cnt2   = (int*)ws;                   ws += 2048 * 4;
    int*    off    = (int*)ws;                   ws += 2064 * 4;               // 2049 used
    float4* binned = (float4*)ws;                ws += (size_t)N2T * 16;       // 256 KB
    bhalf*  wb1fh  = (bhalf*)ws;                 ws += 4096 * 2;
    bhalf*  wb1fl  = (bhalf*)ws;                 ws += 4096 * 2;
    bhalf*  wb1dh  = (bhalf*)ws;                 ws += 4096 * 2;
    bhalf*  wb1dl  = (bhalf*)ws;                 ws += 4096 * 2;
    bhalf*  wb2fh  = (bhalf*)ws;                 ws += 8192 * 2;
    bhalf*  wb2fl  = (bhalf*)ws;                 ws += 8192 * 2;
    bhalf*  wb2dh  = (bhalf*)ws;                 ws += 8192 * 2;
    bhalf*  wb2dl  = (bhalf*)ws;                 ws += 8192 * 2;

    // weight fp32 -> split bf16 (independent)
    wconv_kernel<<<32, 256, 0, stream>>>(w1_feat, w1_dir, w2_feat, w2_dir,
                                         wb1fh, wb1fl, wb1dh, wb1dl,
                                         wb2fh, wb2fl, wb2dh, wb2dl);

    // ---- kNN chain ----
    zero_kernel<<<16, 256, 0, stream>>>(counts, 4096);        // counts + cnt2 (contiguous)
    bin_count_kernel<<<N2T/256, 256, 0, stream>>>(p2, counts);
    scan_kernel<<<1, 256, 0, stream>>>(counts, off);
    bin_scatter_kernel<<<N2T/256, 256, 0, stream>>>(p2, off, cnt2, binned);
    knn_grid_kernel<<<(4*N1T)/256, 256, 0, stream>>>(p1, binned, off, idxs, wts);

    // y2 = VN(x2) -> point-major [N2][192]
    vn_mfma_kernel<128, N2T, false, 1><<<N2T/32, 512, 0, stream>>>(
        x2, wb2fh, wb2fl, wb2dh, wb2dl, nullptr, nullptr, nullptr, y2t);
    // out = VN(x1) + interpolate(y2): channel-major, fused gather, 2-tile pipeline
    vn_mfma_kernel<64, N1T, true, 2><<<N1T/64, 512, 0, stream>>>(
        x1, wb1fh, wb1fl, wb1dh, wb1dl, idxs, wts, y2t, out);
}

// Round 19
// 98.335 us; speedup vs baseline: 1.1278x; 1.1278x over previous
//
#include <hip/hip_runtime.h>

// Problem constants (setup_inputs is fixed):
//   b=4, n1=16384, n2=4096  -> N1=65536 fine points, N2=16384 coarse points
//   Cin(x1)=64, Cin(x2)=128, Cout=64
#define N1T 65536
#define N2T 16384
#define COUT 64
#define CH 192            // Cout*3 channels, point-major
#define GRD 8             // knn grid resolution per dim
#define HCELL 0.125f

typedef unsigned short bhalf;
typedef __attribute__((ext_vector_type(8))) short short8;   // 8 bf16 (4 VGPRs)
typedef __attribute__((ext_vector_type(4))) float f32x4;    // MFMA C/D

__device__ __forceinline__ bhalf f2bf(float f) {
    unsigned u = __float_as_uint(f);
    return (bhalf)((u + 0x7FFFu + ((u >> 16) & 1u)) >> 16);   // RNE
}
__device__ __forceinline__ float bf2f(bhalf h) {
    return __uint_as_float(((unsigned)h) << 16);
}

// ---------------------------------------------------------------------------
// Weight preconversion fp32 -> split bf16 (hi + lo residual), once, tiny.
// ---------------------------------------------------------------------------
__global__ __launch_bounds__(256) void wconv_kernel(
    const float* __restrict__ w1f, const float* __restrict__ w1d,
    const float* __restrict__ w2f, const float* __restrict__ w2d,
    bhalf* __restrict__ o1fh, bhalf* __restrict__ o1fl,
    bhalf* __restrict__ o1dh, bhalf* __restrict__ o1dl,
    bhalf* __restrict__ o2fh, bhalf* __restrict__ o2fl,
    bhalf* __restrict__ o2dh, bhalf* __restrict__ o2dl) {
    const int i = blockIdx.x * 256 + threadIdx.x;   // grid 32 -> 8192
    if (i < 4096) {
        const float a = w1f[i]; const bhalf ah = f2bf(a);
        o1fh[i] = ah; o1fl[i] = f2bf(a - bf2f(ah));
        const float b = w1d[i]; const bhalf bh = f2bf(b);
        o1dh[i] = bh; o1dl[i] = f2bf(b - bf2f(bh));
    }
    const float a = w2f[i]; const bhalf ah = f2bf(a);
    o2fh[i] = ah; o2fl[i] = f2bf(a - bf2f(ah));
    const float b = w2d[i]; const bhalf bh = f2bf(b);
    o2dh[i] = bh; o2dl[i] = f2bf(b - bf2f(bh));
}

// ---------------------------------------------------------------------------
// VN linear + leaky-ReLU via SPLIT-PRECISION bf16 MFMA (R17 schedule —
// empirically best vn1 at 57us; R18's deeper gather prefetch raised reg
// pressure and regressed).
// W.x ~= Wh.xh + Wl.xh + Wh.xl (~2^-16 relative; plain bf16 failed at
// absmax 0.32: VN amplifies d-rounding by |p|/|d|).
// 32-pt tiles, 512 thr = 8 light waves; wave w owns (ot=w&3, sW=w>>2).
// NT=2 tiles/block, double-buffered LDS: load(t1) in flight across
// compute(t0). LDS XOR swizzle col^=((pt>>2)&3)<<3. CM=true fuses
// interpolation-add: per-thread gather of y2t[k][ch..ch+12].
// D-layout (m89): col=lane&15 -> point, row=(lane>>4)*4+reg -> o.
// ---------------------------------------------------------------------------
template<int CIN, int N, bool CM, int NT>
__global__ __launch_bounds__(512) void vn_mfma_kernel(
    const float* __restrict__ x,    // [CIN][3][N]
    const bhalf* __restrict__ wfh, const bhalf* __restrict__ wfl,  // [COUT][CIN]
    const bhalf* __restrict__ wdh, const bhalf* __restrict__ wdl,
    const int*   __restrict__ idxs, // [3][N1] (CM only)
    const float* __restrict__ wts,  // [3][N1] (CM only)
    const float* __restrict__ y2t,  // [N2][192] (CM only)
    float* __restrict__ out)
{
    constexpr int ROWS = CIN * 3;
    constexpr int LDSC = CIN * 3 + 8;    // ushort row stride (16B-aligned)
    constexpr int NB   = (NT > 1) ? 2 : 1;
    constexpr int NLD  = ROWS * 8 / 512; // float4 rounds/tile: 3 (vn1) / 6 (vn2)
    __shared__ __align__(16) bhalf xs_h[NB][32][LDSC];
    __shared__ __align__(16) bhalf xs_l[NB][32][LDSC];

    const int tid  = threadIdx.x;
    const int lane = tid & 63;
    const int wave = tid >> 6;                  // 0..7
    const int r16  = lane & 15;
    const int hh   = lane >> 4;                 // k-group 0..3
    const int ot   = wave & 3;                  // o-tile (16 o's)
    const int sW   = wave >> 2;                 // point subtile (16 pts)
    const int pt   = sW * 16 + r16;
    const int tile0 = blockIdx.x * NT;

    // ---- per-tile neighbor metadata, prefetched for ALL tiles (CM) ----
    int gk[NT][3]; float gw[NT][3];
    if constexpr (CM) {
#pragma unroll
        for (int t = 0; t < NT; ++t) {
            const int n = (tile0 + t) * 32 + pt;
#pragma unroll
            for (int r = 0; r < 3; ++r) {
                gk[t][r] = idxs[r * N1T + n];
                gw[t][r] = wts[r * N1T + n];
            }
        }
    }

    const int wofs = (ot * 16 + r16) * CIN + hh * 8;
    const bhalf* __restrict__ pfh = wfh + wofs;
    const bhalf* __restrict__ pfl = wfl + wofs;
    const bhalf* __restrict__ pdh = wdh + wofs;
    const bhalf* __restrict__ pdl = wdl + wofs;
    // read-side swizzle: (pt>>2)&3 == (r16>>2)&3 (sW*16>>2 ≡ 0 mod 4)
    const int hs = ((hh ^ (r16 >> 2)) & 3) * 8;

    auto LOADT = [&](float4 (&st)[NLD], int t) {
#pragma unroll
        for (int r = 0; r < NLD; ++r) {
            const int i4 = r * 512 + tid;
            const int row = i4 >> 3, p4 = i4 & 7;   // row = c*3+v
            st[r] = *(const float4*)&x[(size_t)row * N + (size_t)(tile0 + t) * 32 + p4 * 4];
        }
    };
    auto WRITET = [&](const float4 (&st)[NLD], int b) {
#pragma unroll
        for (int r = 0; r < NLD; ++r) {
            const int i4 = r * 512 + tid;
            const int row = i4 >> 3, p4 = i4 & 7;
            const int c = row / 3, vv = row - c * 3;
            const int colS = (vv * CIN + c) ^ ((p4 & 3) << 3);
            const float vals[4] = {st[r].x, st[r].y, st[r].z, st[r].w};
#pragma unroll
            for (int j = 0; j < 4; ++j) {
                const bhalf h = f2bf(vals[j]);
                xs_h[b][p4*4+j][colS] = h;
                xs_l[b][p4*4+j][colS] = f2bf(vals[j] - bf2f(h));
            }
        }
    };
    auto COMPUTET = [&](int t, int b, const int (&gkt)[3], const float (&gwt)[3]) {
        const f32x4 zero = {0.f, 0.f, 0.f, 0.f};
        f32x4 accP[3], accD[3];
#pragma unroll
        for (int v = 0; v < 3; ++v) { accP[v] = zero; accD[v] = zero; }
#pragma unroll
        for (int k = 0; k < CIN / 32; ++k) {
            const short8 afh = *(const short8*)(pfh + k * 32);
            const short8 afl = *(const short8*)(pfl + k * 32);
            const short8 adh = *(const short8*)(pdh + k * 32);
            const short8 adl = *(const short8*)(pdl + k * 32);
#pragma unroll
            for (int v = 0; v < 3; ++v) {
                const short8 bh = *(const short8*)&xs_h[b][pt][v * CIN + k * 32 + hs];
                const short8 bl = *(const short8*)&xs_l[b][pt][v * CIN + k * 32 + hs];
                accP[v] = __builtin_amdgcn_mfma_f32_16x16x32_bf16(afh, bh, accP[v], 0, 0, 0);
                accP[v] = __builtin_amdgcn_mfma_f32_16x16x32_bf16(afl, bh, accP[v], 0, 0, 0);
                accP[v] = __builtin_amdgcn_mfma_f32_16x16x32_bf16(afh, bl, accP[v], 0, 0, 0);
                accD[v] = __builtin_amdgcn_mfma_f32_16x16x32_bf16(adh, bh, accD[v], 0, 0, 0);
                accD[v] = __builtin_amdgcn_mfma_f32_16x16x32_bf16(adl, bh, accD[v], 0, 0, 0);
                accD[v] = __builtin_amdgcn_mfma_f32_16x16x32_bf16(adh, bl, accD[v], 0, 0, 0);
            }
        }
        float rr[12];
#pragma unroll
        for (int reg = 0; reg < 4; ++reg) {
            const float p0 = accP[0][reg], p1 = accP[1][reg], p2 = accP[2][reg];
            const float q0 = accD[0][reg], q1 = accD[1][reg], q2 = accD[2][reg];
            const float dot = p0*q0 + p1*q1 + p2*q2;
            const float dd  = q0*q0 + q1*q1 + q2*q2;
            const float coef = (dot < 0.f) ? (0.8f * dot / (dd + 1e-6f)) : 0.f;
            rr[reg*3+0] = p0 - coef * q0;
            rr[reg*3+1] = p1 - coef * q1;
            rr[reg*3+2] = p2 - coef * q2;
        }
        const int n = (tile0 + t) * 32 + pt;
        if constexpr (!CM) {
            float* op = out + (size_t)n * CH + ot * 48 + hh * 12;
            *(float4*)&op[0] = make_float4(rr[0], rr[1], rr[2],  rr[3]);
            *(float4*)&op[4] = make_float4(rr[4], rr[5], rr[6],  rr[7]);
            *(float4*)&op[8] = make_float4(rr[8], rr[9], rr[10], rr[11]);
        } else {
            const int chb = ot * 48 + hh * 12;
            const float* __restrict__ r0 = y2t + (size_t)gkt[0] * CH + chb;
            const float* __restrict__ r1 = y2t + (size_t)gkt[1] * CH + chb;
            const float* __restrict__ r2 = y2t + (size_t)gkt[2] * CH + chb;
            const float w0 = gwt[0], w1 = gwt[1], w2 = gwt[2];
            float4 a0[3], a1[3], a2[3];
#pragma unroll
            for (int q = 0; q < 3; ++q) {
                a0[q] = *(const float4*)&r0[q * 4];
                a1[q] = *(const float4*)&r1[q * 4];
                a2[q] = *(const float4*)&r2[q * 4];
            }
#pragma unroll
            for (int q = 0; q < 3; ++q) {
                const float u0 = w0*a0[q].x + w1*a1[q].x + w2*a2[q].x;
                const float u1 = w0*a0[q].y + w1*a1[q].y + w2*a2[q].y;
                const float u2 = w0*a0[q].z + w1*a1[q].z + w2*a2[q].z;
                const float u3 = w0*a0[q].w + w1*a1[q].w + w2*a2[q].w;
                out[(size_t)(chb + q*4 + 0) * N + n] = rr[q*4+0] + u0;
                out[(size_t)(chb + q*4 + 1) * N + n] = rr[q*4+1] + u1;
                out[(size_t)(chb + q*4 + 2) * N + n] = rr[q*4+2] + u2;
                out[(size_t)(chb + q*4 + 3) * N + n] = rr[q*4+3] + u3;
            }
        }
    };

    float4 stA[NLD], stB[NLD];
    LOADT(stA, 0);
    WRITET(stA, 0);
    if constexpr (NT == 2) {
        LOADT(stB, 1);              // in flight across compute(0)
        __syncthreads();            // buf0 ready
        COMPUTET(0, 0, gk[0], gw[0]);
        WRITET(stB, 1);             // drain + fill buf1
        __syncthreads();            // buf1 ready (and buf0 fully read)
        COMPUTET(1, 1, gk[1], gw[1]);
    } else {
        __syncthreads();
        COMPUTET(0, 0, gk[0], gw[0]);
    }
}

// ---------------------------------------------------------------------------
// kNN via uniform-grid binning. Branchless full-precision top-3 insert.
// ---------------------------------------------------------------------------
#define KNN_INSERT(d2, j)                                        \
    {                                                            \
        const bool c0 = (d2) < b0;                               \
        const bool c1 = (d2) < b1;                               \
        const bool c2 = (d2) < b2v;                              \
        const float nb2 = c2 ? (c1 ? b1 : (d2)) : b2v;           \
        const int   ni2 = c2 ? (c1 ? i1 : (j))  : i2;            \
        const float nb1 = c1 ? (c0 ? b0 : (d2)) : b1;            \
        const int   ni1 = c1 ? (c0 ? i0 : (j))  : i1;            \
        b0 = c0 ? (d2) : b0;  i0 = c0 ? (j) : i0;                \
        b1 = nb1; i1 = ni1; b2v = nb2; i2 = ni2;                 \
    }

__global__ __launch_bounds__(256) void zero_kernel(int* __restrict__ p, int n) {
    const int i = blockIdx.x * 256 + threadIdx.x;
    if (i < n) p[i] = 0;
}

__device__ __forceinline__ int cell_of(float x, float y, float z) {
    int cx = (int)(x * (float)GRD); cx = cx < 0 ? 0 : (cx > GRD-1 ? GRD-1 : cx);
    int cy = (int)(y * (float)GRD); cy = cy < 0 ? 0 : (cy > GRD-1 ? GRD-1 : cy);
    int cz = (int)(z * (float)GRD); cz = cz < 0 ? 0 : (cz > GRD-1 ? GRD-1 : cz);
    return (cz << 6) | (cy << 3) | cx;
}

__global__ __launch_bounds__(256) void bin_count_kernel(
    const float* __restrict__ p2, int* __restrict__ counts) {
    const int i = blockIdx.x * 256 + threadIdx.x;      // 0..16383
    const float x = p2[i*3+0], y = p2[i*3+1], z = p2[i*3+2];
    const int cell = ((i >> 12) << 9) | cell_of(x, y, z);
    atomicAdd(&counts[cell], 1);
}

// exclusive scan of counts[2048] -> off[0..2048]
__global__ __launch_bounds__(256) void scan_kernel(
    const int* __restrict__ counts, int* __restrict__ off) {
    __shared__ int buf[2][256];
    const int t = threadIdx.x;
    int v[8]; int s = 0;
#pragma unroll
    for (int j = 0; j < 8; ++j) { const int tmp = counts[t*8+j]; v[j] = s; s += tmp; }
    buf[0][t] = s; __syncthreads();
    int src = 0;
    for (int d = 1; d < 256; d <<= 1) {
        int val = buf[src][t];
        if (t >= d) val += buf[src][t - d];
        buf[src ^ 1][t] = val; src ^= 1; __syncthreads();
    }
    const int incl = buf[src][t];
    const int base = incl - s;
#pragma unroll
    for (int j = 0; j < 8; ++j) off[t*8+j] = base + v[j];
    if (t == 255) off[2048] = incl;
}

__global__ __launch_bounds__(256) void bin_scatter_kernel(
    const float* __restrict__ p2, const int* __restrict__ off,
    int* __restrict__ cnt2, float4* __restrict__ binned) {
    const int i = blockIdx.x * 256 + threadIdx.x;      // 0..16383
    const float x = p2[i*3+0], y = p2[i*3+1], z = p2[i*3+2];
    const int cell = ((i >> 12) << 9) | cell_of(x, y, z);
    const int pos = off[cell] + atomicAdd(&cnt2[cell], 1);
    binned[pos] = make_float4(x, y, z, __int_as_float(i));
}

// R19: 27 cell-loops -> 9 ROW-loops. For fixed (ny,nz), cells cx-1..cx+1
// are contiguous in the cell index, so their binned ranges form ONE span
// [off[cb+x0], off[cb+x1+1]): 3x less per-range overhead, ~24-pt inner
// loops. Same candidate set; exactness check unchanged.
// 4 lanes per query; butterfly shfl-xor merge (width 4).
__global__ __launch_bounds__(256) void knn_grid_kernel(
    const float* __restrict__ p1,      // [N1][3]
    const float4* __restrict__ binned, // [N2] (x,y,z,idx)
    const int* __restrict__ off,       // [2049]
    int*   __restrict__ idx_out,       // [3][N1]
    float* __restrict__ w_out)         // [3][N1]
{
    const int t   = blockIdx.x * 256 + threadIdx.x;
    const int fp  = t >> 2;
    const int sub = t & 3;
    const int bi  = fp >> 14;
    const int cbase = bi << 9;

    const float qx = p1[fp*3+0], qy = p1[fp*3+1], qz = p1[fp*3+2];
    int cx = (int)(qx * (float)GRD); cx = cx < 0 ? 0 : (cx > 7 ? 7 : cx);
    int cy = (int)(qy * (float)GRD); cy = cy < 0 ? 0 : (cy > 7 ? 7 : cy);
    int cz = (int)(qz * (float)GRD); cz = cz < 0 ? 0 : (cz > 7 ? 7 : cz);

    const int x0 = cx > 0 ? cx - 1 : 0;
    const int x1 = cx < 7 ? cx + 1 : 7;

    float b0 = 1e30f, b1 = 1e30f, b2v = 1e30f;
    int   i0 = 0,     i1 = 0,     i2 = 0;

#pragma unroll
    for (int dz = -1; dz <= 1; ++dz) {
        const int nz = cz + dz;
        if ((unsigned)nz > 7u) continue;
#pragma unroll
        for (int dy = -1; dy <= 1; ++dy) {
            const int ny = cy + dy;
            if ((unsigned)ny > 7u) continue;
            const int cb = cbase + (nz << 6) + (ny << 3);
            const int s = off[cb + x0], e = off[cb + x1 + 1];
            for (int k = s + sub; k < e; k += 4) {
                const float4 c4 = binned[k];
                const float ddx = qx - c4.x, ddy = qy - c4.y, ddz = qz - c4.z;
                const float d2 = fmaf(ddx, ddx, fmaf(ddy, ddy, ddz * ddz));
                const int j = __float_as_int(c4.w);
                KNN_INSERT(d2, j)
            }
        }
    }

    // butterfly merge across the 4 sub-lanes
#pragma unroll
    for (int m = 1; m <= 2; m <<= 1) {
        const float c0v = __shfl_xor(b0, m, 4);
        const float c1v = __shfl_xor(b1, m, 4);
        const float c2v = __shfl_xor(b2v, m, 4);
        const int   j0v = __shfl_xor(i0, m, 4);
        const int   j1v = __shfl_xor(i1, m, 4);
        const int   j2v = __shfl_xor(i2, m, 4);
        KNN_INSERT(c0v, j0v)
        KNN_INSERT(c1v, j1v)
        KNN_INSERT(c2v, j2v)
    }

    // exactness check: nearest unscanned region (walls beyond [0,1] excluded)
    float dw = 1e30f;
    if (cx >= 2) dw = fminf(dw, qx - (float)(cx - 1) * HCELL);
    if (cx <= 5) dw = fminf(dw, (float)(cx + 2) * HCELL - qx);
    if (cy >= 2) dw = fminf(dw, qy - (float)(cy - 1) * HCELL);
    if (cy <= 5) dw = fminf(dw, (float)(cy + 2) * HCELL - qy);
    if (cz >= 2) dw = fminf(dw, qz - (float)(cz - 1) * HCELL);
    if (cz <= 5) dw = fminf(dw, (float)(cz + 2) * HCELL - qz);
    const bool done = b2v < dw * dw;

    if (!done) {   // rare; quad-uniform predicate (post-merge state identical)
        b0 = b1 = b2v = 1e30f; i0 = i1 = i2 = 0;
        const int s = bi << 12, e = (bi + 1) << 12;
        for (int k = s + sub; k < e; k += 4) {
            const float4 c4 = binned[k];
            const float ddx = qx - c4.x, ddy = qy - c4.y, ddz = qz - c4.z;
            const float d2 = fmaf(ddx, ddx, fmaf(ddy, ddy, ddz * ddz));
            const int j = __float_as_int(c4.w);
            KNN_INSERT(d2, j)
        }
#pragma unroll
        for (int m = 1; m <= 2; m <<= 1) {
            const float c0v = __shfl_xor(b0, m, 4);
            const float c1v = __shfl_xor(b1, m, 4);
            const float c2v = __shfl_xor(b2v, m, 4);
            const int   j0v = __shfl_xor(i0, m, 4);
            const int   j1v = __shfl_xor(i1, m, 4);
            const int   j2v = __shfl_xor(i2, m, 4);
            KNN_INSERT(c0v, j0v)
            KNN_INSERT(c1v, j1v)
            KNN_INSERT(c2v, j2v)
        }
    }

    if (sub == 0) {
        const float w0 = 1.f / (b0 + 1e-8f);
        const float w1 = 1.f / (b1 + 1e-8f);
        const float w2 = 1.f / (b2v + 1e-8f);
        const float inv = 1.f / (w0 + w1 + w2);
        idx_out[0*N1T + fp] = i0;
        idx_out[1*N1T + fp] = i1;
        idx_out[2*N1T + fp] = i2;
        w_out[0*N1T + fp] = w0 * inv;
        w_out[1*N1T + fp] = w1 * inv;
        w_out[2*N1T + fp] = w2 * inv;
    }
}

// ---------------------------------------------------------------------------
extern "C" void kernel_launch(void* const* d_in, const int* in_sizes, int n_in,
                              void* d_out, int out_size, void* d_ws, size_t ws_size,
                              hipStream_t stream) {
    const float* p1      = (const float*)d_in[0];
    const float* x1      = (const float*)d_in[1];
    const float* p2      = (const float*)d_in[3];
    const float* x2      = (const float*)d_in[4];
    const float* w1_feat = (const float*)d_in[6];
    const float* w1_dir  = (const float*)d_in[7];
    const float* w2_feat = (const float*)d_in[8];
    const float* w2_dir  = (const float*)d_in[9];
    float* out = (float*)d_out;

    // workspace layout (all chunks 16B-aligned)
    char* ws = (char*)d_ws;
    float*  y2t    = (float*)ws;                 ws += (size_t)N2T * CH * 4;   // 12.58 MB
    int*    idxs   = (int*)ws;                   ws += (size_t)3 * N1T * 4;    // 0.75 MB
    float*  wts    = (float*)ws;                 ws += (size_t)3 * N1T * 4;    // 0.75 MB
    int*    counts = (int*)ws;                   ws += 2048 * 4;
    int*    cnt2   = (int*)ws;                   ws += 2048 * 4;
    int*    off    = (int*)ws;                   ws += 2064 * 4;               // 2049 used
    float4* binned = (float4*)ws;                ws += (size_t)N2T * 16;       // 256 KB
    bhalf*  wb1fh  = (bhalf*)ws;                 ws += 4096 * 2;
    bhalf*  wb1fl  = (bhalf*)ws;                 ws += 4096 * 2;
    bhalf*  wb1dh  = (bhalf*)ws;                 ws += 4096 * 2;
    bhalf*  wb1dl  = (bhalf*)ws;                 ws += 4096 * 2;
    bhalf*  wb2fh  = (bhalf*)ws;                 ws += 8192 * 2;
    bhalf*  wb2fl  = (bhalf*)ws;                 ws += 8192 * 2;
    bhalf*  wb2dh  = (bhalf*)ws;                 ws += 8192 * 2;
    bhalf*  wb2dl  = (bhalf*)ws;                 ws += 8192 * 2;

    // weight fp32 -> split bf16 (independent)
    wconv_kernel<<<32, 256, 0, stream>>>(w1_feat, w1_dir, w2_feat, w2_dir,
                                         wb1fh, wb1fl, wb1dh, wb1dl,
                                         wb2fh, wb2fl, wb2dh, wb2dl);

    // ---- kNN chain ----
    zero_kernel<<<16, 256, 0, stream>>>(counts, 4096);        // counts + cnt2 (contiguous)
    bin_count_kernel<<<N2T/256, 256, 0, stream>>>(p2, counts);
    scan_kernel<<<1, 256, 0, stream>>>(counts, off);
    bin_scatter_kernel<<<N2T/256, 256, 0, stream>>>(p2, off, cnt2, binned);
    knn_grid_kernel<<<(4*N1T)/256, 256, 0, stream>>>(p1, binned, off, idxs, wts);

    // y2 = VN(x2) -> point-major [N2][192]
    vn_mfma_kernel<128, N2T, false, 1><<<N2T/32, 512, 0, stream>>>(
        x2, wb2fh, wb2fl, wb2dh, wb2dl, nullptr, nullptr, nullptr, y2t);
    // out = VN(x1) + interpolate(y2): channel-major, fused gather, 2-tile pipeline
    vn_mfma_kernel<64, N1T, true, 2><<<N1T/64, 512, 0, stream>>>(
        x1, wb1fh, wb1fl, wb1dh, wb1dl, idxs, wts, y2t, out);
}